// Round 15
// baseline (49.845 us; speedup 1.0000x reference)
//
#include <hip/hip_runtime.h>
#include <math.h>

#define MLEN 4096
#define LOG2M 12
#define RANK 8
#define NSAMP 2048
#define VEC 8      // consecutive m-points per thread

__device__ __forceinline__ float softplus_f(float x) {
    return (x > 20.0f) ? x : log1pf(expf(x));
}

// ---------------------------------------------------------------------------
// Kernel 1: PROVEN radix-2 DIT FFT (R6/R10 version, measured 9.7 us,
// absmax 1.0). One block of 1024 per row; 32 KB LDS; natural-order output.
// ---------------------------------------------------------------------------
__global__ __launch_bounds__(1024) void fft_rows_kernel(const float* __restrict__ H,
                                                        float2* __restrict__ Hft) {
    __shared__ float2 buf[MLEN];            // 32 KB
    const int d = blockIdx.x;
    const float* row = H + d * MLEN;

    for (int i = threadIdx.x; i < MLEN; i += 1024) {
        int src = (int)(__brev((unsigned)i) >> (32 - LOG2M));
        buf[i] = make_float2(softplus_f(row[src]), 0.0f);
    }
    __syncthreads();

    for (int s = 1; s <= LOG2M; ++s) {
        const int half = 1 << (s - 1);
#pragma unroll 2
        for (int p = threadIdx.x; p < (MLEN >> 1); p += 1024) {
            const int k  = p & (half - 1);
            const int i0 = ((p >> (s - 1)) << s) + k;
            const int i1 = i0 + half;
            const float ang = -6.28318530717958647692f * (float)k / (float)(half << 1);
            const float sw = __sinf(ang);
            const float cw = __cosf(ang);
            float2 a = buf[i0];
            float2 b = buf[i1];
            float tr = b.x * cw - b.y * sw;
            float ti = b.x * sw + b.y * cw;
            buf[i0] = make_float2(a.x + tr, a.y + ti);
            buf[i1] = make_float2(a.x - tr, a.y - ti);
        }
        __syncthreads();
    }

    float2* outrow = Hft + d * MLEN;
    for (int i = threadIdx.x; i < MLEN; i += 1024) outrow[i] = buf[i];
}

// ---------------------------------------------------------------------------
// Kernel 2: V[n,m] = sum_d softplus(W[n,d]) * exp(-i*2pi*tau[n,d]*m/M) * Hft[d,m]
// VEC=8 consecutive m, NS=1. Rationale (R14 post-mortem):
//   trig/output = 2*RANK/VEC regardless of NS -> full amortization at VEC=8;
//   NS=1 shrinks footprint to ~50 VGPR -> 8 waves/SIMD resident, 16384 waves
//   total -> TLP hides L2 latency (R12's 4 waves/SIMD was latency-bound).
// No manual double-buffer. d-loop unroll 1 (anti-hoist, R8 lesson).
// Grid: (MLEN/(256*VEC)=2, NSAMP=2048) blocks of 256.
// ---------------------------------------------------------------------------
template <int REAL_ONLY>
__global__ __launch_bounds__(256) void mix_kernel(const float* __restrict__ W,
                                                  const float* __restrict__ tau,
                                                  const float2* __restrict__ Hft,
                                                  float* __restrict__ out) {
    const int tid = threadIdx.x;
    const int m0  = (blockIdx.x * 256 + tid) * VEC;
    const int n   = blockIdx.y;

    __shared__ float  s_spw[RANK];
    __shared__ float  s_tau[RANK];
    __shared__ float2 s_step[RANK];         // exp(-i*2pi*tau/M), thread-uniform
    if (tid < RANK) {
        const float t = tau[n * RANK + tid];
        s_spw[tid] = softplus_f(W[n * RANK + tid]);
        s_tau[tid] = t;
        const float a1 = -1.53398078788564122971e-3f * t;   // -2*pi/4096 * t
        s_step[tid] = make_float2(__cosf(a1), __sinf(a1));
    }
    __syncthreads();

    float ar[VEC];
    float ai[VEC];   // dead (DCE) in REAL_ONLY instantiation
#pragma unroll
    for (int k = 0; k < VEC; ++k) { ar[k] = 0.0f; ai[k] = 0.0f; }

    const float thm = -6.28318530717958647692f * ((float)m0 * (1.0f / (float)MLEN));

#pragma unroll 1
    for (int d = 0; d < RANK; ++d) {
        // loads first: 4 x dwordx4, independent of the trig below
        const float4* hp = reinterpret_cast<const float4*>(Hft + (size_t)d * MLEN + m0);
        const float4 h0 = hp[0], h1 = hp[1], h2 = hp[2], h3 = hp[3];

        const float t   = s_tau[d];
        const float a0  = thm * t;
        const float spw = s_spw[d];
        float cs = spw * __cosf(a0);         // phasor pre-scaled by softplus(W)
        float sn = spw * __sinf(a0);
        const float2 st = s_step[d];
        const float dc = st.x, ds = st.y;

#pragma unroll
        for (int k = 0; k < VEC; ++k) {
            const float4& hq = (k < 2) ? h0 : (k < 4) ? h1 : (k < 6) ? h2 : h3;
            const float hx = (k & 1) ? hq.z : hq.x;
            const float hy = (k & 1) ? hq.w : hq.y;
            ar[k] += cs * hx - sn * hy;
            if (!REAL_ONLY) ai[k] += cs * hy + sn * hx;
            if (k < VEC - 1) {               // last rotation is dead
                const float ncs = cs * dc - sn * ds;
                sn = cs * ds + sn * dc;
                cs = ncs;
            }
        }
    }

    if (REAL_ONLY) {
        float* po = out + (size_t)n * MLEN + m0;
        reinterpret_cast<float4*>(po)[0] = make_float4(ar[0], ar[1], ar[2], ar[3]);
        reinterpret_cast<float4*>(po)[1] = make_float4(ar[4], ar[5], ar[6], ar[7]);
    } else {
        float2* po = (float2*)out + (size_t)n * MLEN + m0;
#pragma unroll
        for (int q = 0; q < 4; ++q) {
            reinterpret_cast<float4*>(po)[q] =
                make_float4(ar[2 * q], ai[2 * q], ar[2 * q + 1], ai[2 * q + 1]);
        }
    }
}

extern "C" void kernel_launch(void* const* d_in, const int* in_sizes, int n_in,
                              void* d_out, int out_size, void* d_ws, size_t ws_size,
                              hipStream_t stream) {
    const float* W   = (const float*)d_in[0];   // (N, R)
    const float* H   = (const float*)d_in[1];   // (R, M)
    const float* tau = (const float*)d_in[2];   // (N, R)
    float2* Hft = (float2*)d_ws;                // (R, M) complex, 256 KB
    float* out  = (float*)d_out;

    fft_rows_kernel<<<RANK, 1024, 0, stream>>>(H, Hft);

    const long long NM = (long long)NSAMP * MLEN;
    dim3 grid(MLEN / (256 * VEC), NSAMP);
    if ((long long)out_size >= 2 * NM) {
        mix_kernel<0><<<grid, 256, 0, stream>>>(W, tau, Hft, out);
    } else {
        mix_kernel<1><<<grid, 256, 0, stream>>>(W, tau, Hft, out);
    }
}